// Round 6
// baseline (2565.969 us; speedup 1.0000x reference)
//
#include <hip/hip_runtime.h>
#include <hip/hip_bf16.h>
#include <math.h>

// Problem constants
#define VV   32000
#define DD   300
#define HU   300
#define NC   3
#define BB   128
#define TT   512
#define N4H  1200
#define CHUNK 64
#define NCHUNK (TT / CHUNK)

// Recurrent kernel partition (round-0 proven structure)
#define GC   15   // col groups (units)
#define GR   16   // row groups
#define RPW  8    // rows per WG (BB/GR)
#define UPW  20   // units per WG (HU/GC)
#define KSW  96   // k-window per wave (4 waves x 96 covers 300 w/ zero pad)
#define HLB_STRIDE 312            // h plane row stride in shorts (624B: 16B-aligned, 2-way bank alias = free)
#define HLB_SIZE   (16 * HLB_STRIDE + 32)

// Workspace layout: [zx (float)][ex (ulong, tagged h exchange)][cst][hfin]
static constexpr size_t ZX_F   = (size_t)BB * CHUNK * N4H;   // 9,830,400 floats
static constexpr size_t EX_W   = (size_t)2 * GR * RPW * HU;  // 76,800 ulongs
static constexpr size_t CST_F  = (size_t)BB * HU;            // 38,400 floats
static constexpr size_t HFIN_F = (size_t)BB * HU;            // 38,400 floats

typedef __attribute__((ext_vector_type(8))) short bf16x8;
typedef __attribute__((ext_vector_type(8))) _Float16 f16x8;
typedef __attribute__((ext_vector_type(4))) float f32x4;
typedef unsigned long long ull;

__device__ __forceinline__ short f2bf(float f) {
    unsigned u = __float_as_uint(f);
    u += 0x7fff + ((u >> 16) & 1);   // round-to-nearest-even
    return (short)(u >> 16);
}
__device__ __forceinline__ short f2h(float f) {   // float -> f16 bits (RTNE)
    _Float16 h = (_Float16)f;
    return *(short*)&h;
}
__device__ __forceinline__ float h2f(short s) {
    _Float16 h = *(_Float16*)&s;
    return (float)h;
}
__device__ __forceinline__ float sigm(float x) { return 1.f / (1.f + __expf(-x)); }
__device__ __forceinline__ float tanh_(float x) { return 1.f - 2.f / (__expf(2.f * x) + 1.f); }

// ---------------------------------------------------------------------------
// init: zero exchange tags, c state, out[0]  (ws is poisoned 0xAA every launch)
// ---------------------------------------------------------------------------
__global__ void init_kernel(ull* __restrict__ ex, float* __restrict__ cst,
                            float* __restrict__ out) {
    size_t i = (size_t)blockIdx.x * 256 + threadIdx.x;
    if (i < EX_W) ex[i] = 0ull;
    if (i < CST_F) cst[i] = 0.f;
    if (i == 0) out[0] = 0.f;
}

// ---------------------------------------------------------------------------
// Phase 1: zx[b][tc][n] = emb[ids[b][t0+tc]] @ W_lstm[0:300] + b_lstm   (bf16 MFMA)
// WG tile: M=256 rows, N=80 cols, K=320 (300 zero-padded). 4 waves, wave = 64x80.
// grid = (8192/256, 1200/80) = (32, 15)   [round-0, verified]
// ---------------------------------------------------------------------------
__global__ __launch_bounds__(256) void zx_gemm(
    const float* __restrict__ emb, const int* __restrict__ ids,
    const float* __restrict__ Wl, const float* __restrict__ bl,
    float* __restrict__ zx, int t0)
{
    __shared__ short A_l[256 * 40];   // [row][k] pad 32->40 shorts
    __shared__ short B_l[80 * 40];    // [col][k] (transposed)
    __shared__ int   ids_l[256];

    const int tid = threadIdx.x;
    const int m0  = blockIdx.x * 256;
    const int n0  = blockIdx.y * 80;
    const int wv  = tid >> 6, ln = tid & 63;

    {   // per-row embedding id
        int m = m0 + tid;
        int b = m >> 6, tc = m & (CHUNK - 1);
        ids_l[tid] = ids[b * TT + t0 + tc];
    }

    f32x4 acc[4][5];
    for (int i = 0; i < 4; ++i)
        for (int j = 0; j < 5; ++j)
            acc[i][j] = (f32x4){0.f, 0.f, 0.f, 0.f};

    for (int k0 = 0; k0 < 320; k0 += 32) {
        __syncthreads();
        // stage A: 256 rows x 32 k, one row per thread (float4 x8, guard k<300)
        {
            const float* src = emb + (size_t)ids_l[tid] * DD;
            #pragma unroll
            for (int q = 0; q < 8; ++q) {
                int kg = k0 + q * 4;
                float4 v;
                if (kg < DD) v = *(const float4*)(src + kg);
                else         v = make_float4(0.f, 0.f, 0.f, 0.f);
                short4 s; s.x = f2bf(v.x); s.y = f2bf(v.y); s.z = f2bf(v.z); s.w = f2bf(v.w);
                *(short4*)&A_l[tid * 40 + q * 4] = s;
            }
        }
        // stage B (transposed): 80 cols x 32 k. thread: kk=tid>>3, 10 cols each
        {
            int kk = tid >> 3;
            int c0 = (tid & 7) * 10;
            int kg = k0 + kk;
            #pragma unroll
            for (int c = 0; c < 10; ++c) {
                float v = (kg < DD) ? Wl[(size_t)kg * N4H + n0 + c0 + c] : 0.f;
                B_l[(c0 + c) * 40 + kk] = f2bf(v);
            }
        }
        __syncthreads();
        // fragments + MFMA. A[m=lane&15][k=quad*8+j], B[k=quad*8+j][n=lane&15]
        const int koff = (ln >> 4) * 8;
        bf16x8 afr[4], bfr[5];
        #pragma unroll
        for (int mt = 0; mt < 4; ++mt) {
            int row = wv * 64 + mt * 16 + (ln & 15);
            afr[mt] = *(const bf16x8*)&A_l[row * 40 + koff];
        }
        #pragma unroll
        for (int nt = 0; nt < 5; ++nt) {
            int col = nt * 16 + (ln & 15);
            bfr[nt] = *(const bf16x8*)&B_l[col * 40 + koff];
        }
        #pragma unroll
        for (int mt = 0; mt < 4; ++mt)
            #pragma unroll
            for (int nt = 0; nt < 5; ++nt)
                acc[mt][nt] = __builtin_amdgcn_mfma_f32_16x16x32_bf16(
                    afr[mt], bfr[nt], acc[mt][nt], 0, 0, 0);
    }
    // epilogue: C row=(lane>>4)*4+reg, col=lane&15; add bias
    #pragma unroll
    for (int mt = 0; mt < 4; ++mt) {
        #pragma unroll
        for (int nt = 0; nt < 5; ++nt) {
            #pragma unroll
            for (int rg = 0; rg < 4; ++rg) {
                int row = m0 + wv * 64 + mt * 16 + (ln >> 4) * 4 + rg;
                int col = n0 + nt * 16 + (ln & 15);
                zx[(size_t)row * N4H + col] = acc[mt][nt][rg] + bl[col];
            }
        }
    }
}

// ---------------------------------------------------------------------------
// Phase 2: persistent recurrent kernel. 240 WGs = 16 row-groups x 15 col-groups.
// ROUND-0 STRUCTURE + R17 payload packing. R18's ONLY change: the sentinel
// phase is DELETED — the per-wave stage goes straight into the pend-masked
// stripe sweep.
//   Rationale: the sentinel spin serializes a full LLC poll round trip
// (until the SLOWEST overlapping producer's tag lands) before the sweep's
// loads even issue, and it delays reading the 14 fast producers' words.
// R12 added sentinels when a failed sweep re-loaded the full 768-word
// stripe; the current pend mask retries ONLY stale words, so retry traffic
// decays geometrically and the fabric-saturation regime sentinels fixed no
// longer exists. Correctness is carried entirely by the sweep's per-word
// tag >= t checks (unchanged) — sentinels were a perf gate only.
//
// Recurrent GEMM: F16 MFMA with h-side split (absmax at 4.88e-4 output floor):
//   z = (h_hi + h_lo) @ W_f16,  h_hi = f16(h), h_lo = f16(h - h_hi)
// W_h f16 fragments live in LDS, fragment-ordered (R10). Per-wave K-window
// waiting + single barrier per step (R11). Producer-side payload packing
// [tag:32 | lo:16 | hi:16] (R17, proven R13/R14).
//
// Tag-ABA safety (transitive, per-wave): publish(s+2) > barrier(s+1)
// > all 4 waves accepted tags s+1 over window-union = all 15 producers'
// s+1 publishes >= every consumer's step-s reads.
//
// NaN guard (R6): both h planes zeroed IN FULL once per dispatch, so wave 3's
// A reads of cols 300..319 are exact 0 (B=0 there; 0*0=0).
// ---------------------------------------------------------------------------
__global__ __launch_bounds__(256, 1) void lstm_rec(
    const float* __restrict__ zx, const float* __restrict__ Wl,
    const int* __restrict__ lens, ull* __restrict__ ex,
    float* __restrict__ cst, float* __restrict__ hfin, int t0)
{
    const int tid = threadIdx.x;
    const int wv  = tid >> 6, ln = tid & 63;
    const int rg  = blockIdx.x % GR;
    const int cgi = blockIdx.x / GR;
    const int r0  = rg * RPW;
    const int u0  = cgi * UPW;
    const int m   = ln & 15;           // MFMA row / col-in-tile
    const int quad = ln >> 4;

    __shared__ short h_hi[HLB_SIZE];        // f16 hi plane of h_{t-1}
    __shared__ short h_lo[HLB_SIZE];        // f16 lo plane of h_{t-1}
    __shared__ float zp[2][4][RPW][84];     // parity x wave k-partials (pad 80->84)
    __shared__ short w_l[4 * 15 * 64 * 8];  // f16 W_h fragments, frag-ordered

    // ---- one-time: pack W_h f16 B-fragments into LDS ----
    // B[k=quad*8+j][n=lane&15]; frag f = s*5+nt covers kstep s, ntile nt.
    #pragma unroll
    for (int s = 0; s < 3; ++s) {
        #pragma unroll
        for (int nt = 0; nt < 5; ++nt) {
            int c    = nt * 16 + m;            // 0..79 within WG cols
            int gate = c / 20;
            int wcol = 300 * gate + u0 + (c % 20);
            f16x8 b;
            #pragma unroll
            for (int j = 0; j < 8; ++j) {
                int k = KSW * wv + 32 * s + quad * 8 + j;
                float v = (k < HU) ? Wl[(size_t)(DD + k) * N4H + wcol] : 0.f;
                b[j] = (_Float16)v;
            }
            *(f16x8*)&w_l[(((wv * 15) + (s * 5 + nt)) * 64 + ln) * 8] = b;
        }
    }
    const int nks = (wv == 3) ? 1 : 3;   // wave 3: only kstep 0 has real k

    // zero BOTH h planes in full once per dispatch (NaN guard + h0 = 0)
    for (int i = tid; i < HLB_SIZE; i += 256) { h_hi[i] = 0; h_lo[i] = 0; }

    // gate role (tid < 160): u = tid%20, r = tid/20; c/h_old in registers
    const int g_u = tid % UPW, g_r = tid / UPW;
    const bool gl = (tid < RPW * UPW);
    float c_reg = 0.f, ho_reg = 0.f;
    int mylen = 0;
    if (gl) {
        c_reg = cst[(size_t)(r0 + g_r) * HU + u0 + g_u];
        mylen = lens[r0 + g_r];
        if (t0 > 0) {   // reload own h_{t0-1} (tag t0, parity t0&1) from last dispatch
            ull v = __hip_atomic_load(
                ex + (((size_t)(t0 & 1) * GR + rg) * RPW + g_r) * HU + u0 + g_u,
                __ATOMIC_RELAXED, __HIP_MEMORY_SCOPE_AGENT);
            unsigned d = (unsigned)v;
            ho_reg = h2f((short)(d & 0xFFFFu)) + h2f((short)(d >> 16));
        }
    }
    __syncthreads();   // h-plane zero + w_l pack visible before first step

    for (int tc = 0; tc < CHUNK; ++tc) {
        const int t = t0 + tc;
        const int par = t & 1;

        // prefetch zx for this step (independent of h)
        float z_pre[4];
        if (gl) {
            const float* zrow = zx + ((size_t)(r0 + g_r) * CHUNK + tc) * N4H;
            #pragma unroll
            for (int gg = 0; gg < 4; ++gg)
                z_pre[gg] = zrow[300 * gg + u0 + g_u];
        }

        // ---- per-wave stage of OWN K-window stripe (no barrier after) ----
        // R18: straight into the pend-masked sweep (sentinel phase deleted).
        if (t > 0) {
            const ull* exb = ex + ((size_t)par * GR + rg) * (RPW * HU);

            if (wv < 3) {
                // 768 words: i = ln + 64k, r = i/96, u = 96*wv + i%96
                unsigned pend = 0xFFFu;
                do {
                    ull v[12];
                    #pragma unroll
                    for (int k = 0; k < 12; ++k)
                        if ((pend >> k) & 1) {
                            int i = ln + (k << 6);
                            int r = i / 96, u = KSW * wv + (i % 96);
                            v[k] = __hip_atomic_load(exb + r * HU + u,
                                                     __ATOMIC_RELAXED,
                                                     __HIP_MEMORY_SCOPE_AGENT);
                        }
                    unsigned got = 0;
                    #pragma unroll
                    for (int k = 0; k < 12; ++k) {
                        if (((pend >> k) & 1) && (int)(v[k] >> 32) >= t) {
                            int i = ln + (k << 6);
                            int r = i / 96, u = KSW * wv + (i % 96);
                            int idx = r * HLB_STRIDE + u;
                            unsigned d = (unsigned)v[k];
                            h_hi[idx] = (short)(d & 0xFFFFu);
                            h_lo[idx] = (short)(d >> 16);
                            got |= 1u << k;
                        }
                    }
                    pend &= ~got;
                    if (pend) __builtin_amdgcn_s_sleep(1);
                } while (pend);
            } else {
                // 96 words: i = ln + 64k (i<96), r = i/12, u = 288 + i%12
                unsigned pend = (ln < 32) ? 0x3u : 0x1u;
                do {
                    ull v[2];
                    #pragma unroll
                    for (int k = 0; k < 2; ++k)
                        if ((pend >> k) & 1) {
                            int i = ln + (k << 6);
                            int r = i / 12, u = 288 + (i % 12);
                            v[k] = __hip_atomic_load(exb + r * HU + u,
                                                     __ATOMIC_RELAXED,
                                                     __HIP_MEMORY_SCOPE_AGENT);
                        }
                    unsigned got = 0;
                    #pragma unroll
                    for (int k = 0; k < 2; ++k) {
                        if (((pend >> k) & 1) && (int)(v[k] >> 32) >= t) {
                            int i = ln + (k << 6);
                            int r = i / 12, u = 288 + (i % 12);
                            int idx = r * HLB_STRIDE + u;
                            unsigned d = (unsigned)v[k];
                            h_hi[idx] = (short)(d & 0xFFFFu);
                            h_lo[idx] = (short)(d >> 16);
                            got |= 1u << k;
                        }
                    }
                    pend &= ~got;
                    if (pend) __builtin_amdgcn_s_sleep(1);
                } while (pend);
            }
        }

        // ---- MFMA on own stripe: A hi/lo from LDS, B f16 from LDS ----
        f32x4 acc[5];
        #pragma unroll
        for (int nt = 0; nt < 5; ++nt) acc[nt] = (f32x4){0.f, 0.f, 0.f, 0.f};
        for (int s = 0; s < nks; ++s) {
            const int aoff = m * HLB_STRIDE + KSW * wv + 32 * s + quad * 8;
            f16x8 ah = *(const f16x8*)&h_hi[aoff];
            f16x8 al = *(const f16x8*)&h_lo[aoff];
            f16x8 bfr[5];
            #pragma unroll
            for (int nt = 0; nt < 5; ++nt)
                bfr[nt] = *(const f16x8*)&w_l[(((wv * 15) + (s * 5 + nt)) * 64 + ln) * 8];
            #pragma unroll
            for (int nt = 0; nt < 5; ++nt)
                acc[nt] = __builtin_amdgcn_mfma_f32_16x16x32_f16(
                    ah, bfr[nt], acc[nt], 0, 0, 0);
            #pragma unroll
            for (int nt = 0; nt < 5; ++nt)
                acc[nt] = __builtin_amdgcn_mfma_f32_16x16x32_f16(
                    al, bfr[nt], acc[nt], 0, 0, 0);
        }
        // C: row=quad*4+reg (lanes 0-31 -> rows 0-7), col=nt*16+m
        if (ln < 32) {
            #pragma unroll
            for (int nt = 0; nt < 5; ++nt)
                #pragma unroll
                for (int r4 = 0; r4 < 4; ++r4)
                    zp[par][wv][quad * 4 + r4][nt * 16 + m] = acc[nt][r4];
        }
        __syncthreads();   // the ONE barrier: zp(t) visible to gate lanes

        // ---- reduce 4 partials + gates + tagged publish (160 threads) ----
        if (gl) {
            const int b = r0 + g_r;
            float z4[4];
            #pragma unroll
            for (int gg = 0; gg < 4; ++gg) {
                int cidx = gg * UPW + g_u;
                z4[gg] = z_pre[gg] + zp[par][0][g_r][cidx] + zp[par][1][g_r][cidx]
                                   + zp[par][2][g_r][cidx] + zp[par][3][g_r][cidx];
            }
            float ig = sigm(z4[0]);
            float jg = tanh_(z4[1]);
            float fg = sigm(z4[2] + 1.0f);   // FORGET_BIAS
            float og = sigm(z4[3]);
            float c_new = c_reg * fg + ig * jg;
            float h_new = tanh_(c_new) * og;
            bool upd = (t < mylen);
            ho_reg = upd ? h_new : ho_reg;
            c_reg  = upd ? c_new : c_reg;
            // publish h_t (tag t+1, parity (t+1)&1), producer-side hi/lo split:
            // [tag:32 | lo:16 | hi:16] — fire & forget (R17; proven R13/R14)
            short hhi = f2h(ho_reg);
            short hlo = f2h(ho_reg - h2f(hhi));
            ull pk = ((ull)(unsigned)(t + 1) << 32)
                   | ((ull)(unsigned short)hlo << 16) | (ull)(unsigned short)hhi;
            __hip_atomic_store(
                ex + (((size_t)((t + 1) & 1) * GR + rg) * RPW + g_r) * HU + u0 + g_u,
                pk, __ATOMIC_RELAXED, __HIP_MEMORY_SCOPE_AGENT);
            if (tc == CHUNK - 1) hfin[(size_t)b * HU + u0 + g_u] = ho_reg;
        }
        // no trailing barrier: per-wave sweep acceptance + the single barrier
        // order all h-stripe and zp reuse (see header proof).
    }
    if (gl) cst[(size_t)(r0 + g_r) * HU + u0 + g_u] = c_reg;
}

// ---------------------------------------------------------------------------
// Phase 3: logits = h_final @ W_dense + b_dense; log-softmax NLL; mean loss.
// One wave per batch row.
// ---------------------------------------------------------------------------
__global__ __launch_bounds__(64) void cls_kernel(
    const float* __restrict__ hfin, const float* __restrict__ Wd,
    const float* __restrict__ bd, const int* __restrict__ labels,
    float* __restrict__ out)
{
    const int b = blockIdx.x;
    const int ln = threadIdx.x;
    const float* h = hfin + (size_t)b * HU;
    float p0 = 0.f, p1 = 0.f, p2 = 0.f;
    for (int k = ln; k < HU; k += 64) {
        float hv = h[k];
        p0 += hv * Wd[k * 3 + 0];
        p1 += hv * Wd[k * 3 + 1];
        p2 += hv * Wd[k * 3 + 2];
    }
    #pragma unroll
    for (int off = 32; off > 0; off >>= 1) {
        p0 += __shfl_down(p0, off);
        p1 += __shfl_down(p1, off);
        p2 += __shfl_down(p2, off);
    }
    if (ln == 0) {
        float l0 = p0 + bd[0], l1 = p1 + bd[1], l2 = p2 + bd[2];
        float m = fmaxf(l0, fmaxf(l1, l2));
        float lse = m + logf(__expf(l0 - m) + __expf(l1 - m) + __expf(l2 - m));
        int lab = labels[b];
        float sel = (lab == 0) ? l0 : ((lab == 1) ? l1 : l2);
        float nll = lse - sel;
        out[1 + b * 3 + 0] = l0;
        out[1 + b * 3 + 1] = l1;
        out[1 + b * 3 + 2] = l2;
        atomicAdd(out, nll * (1.0f / BB));
    }
}

// ---------------------------------------------------------------------------
extern "C" void kernel_launch(void* const* d_in, const int* in_sizes, int n_in,
                              void* d_out, int out_size, void* d_ws, size_t ws_size,
                              hipStream_t stream) {
    const int*   ids  = (const int*)d_in[0];
    const int*   lens = (const int*)d_in[1];
    const int*   labs = (const int*)d_in[2];
    const float* emb  = (const float*)d_in[3];
    const float* Wl   = (const float*)d_in[4];
    const float* bl   = (const float*)d_in[5];
    const float* Wd   = (const float*)d_in[6];
    const float* bd   = (const float*)d_in[7];
    float* out = (float*)d_out;

    float* zx   = (float*)d_ws;
    ull*   ex   = (ull*)(zx + ZX_F);
    float* cst  = (float*)(ex + EX_W);
    float* hfin = cst + CST_F;

    {   // zero exchange tags / c state / out[0]
        int n = (int)((EX_W + 255) / 256);
        init_kernel<<<n, 256, 0, stream>>>(ex, cst, out);
    }
    for (int c = 0; c < NCHUNK; ++c) {
        int t0 = c * CHUNK;
        zx_gemm<<<dim3(32, 15), 256, 0, stream>>>(emb, ids, Wl, bl, zx, t0);
        lstm_rec<<<GR * GC, 256, 0, stream>>>(zx, Wl, lens, ex, cst, hfin, t0);
    }
    cls_kernel<<<BB, 64, 0, stream>>>(hfin, Wd, bd, labs, out);
}

// Round 7
// 2226.026 us; speedup vs baseline: 1.1527x; 1.1527x over previous
//
#include <hip/hip_runtime.h>
#include <hip/hip_bf16.h>
#include <math.h>

// Problem constants
#define VV   32000
#define DD   300
#define HU   300
#define NC   3
#define BB   128
#define TT   512
#define N4H  1200
#define CHUNK 64
#define NCHUNK (TT / CHUNK)

// Recurrent kernel partition (round-0 proven structure)
#define GC   15   // col groups (units)
#define GR   16   // row groups
#define RPW  8    // rows per WG (BB/GR)
#define UPW  20   // units per WG (HU/GC)
#define KSW  96   // k-window per wave (4 waves x 96 covers 300 w/ zero pad)
#define HLB_STRIDE 312            // h plane row stride in shorts (624B: 16B-aligned, 2-way bank alias = free)
#define HLB_SIZE   (16 * HLB_STRIDE + 32)

// Workspace layout: [zx f32][ex ull][cst f32][hfin f32][emb16 bf16][wt bf16]
static constexpr size_t ZX_F    = (size_t)BB * CHUNK * N4H;   // 9,830,400 floats
static constexpr size_t EX_W    = (size_t)2 * GR * RPW * HU;  // 76,800 ulongs
static constexpr size_t CST_F   = (size_t)BB * HU;            // 38,400 floats
static constexpr size_t HFIN_F  = (size_t)BB * HU;            // 38,400 floats
static constexpr size_t EMB16_W = (size_t)VV * 320;           // 10,240,000 shorts (K padded)
static constexpr size_t WT_W    = (size_t)N4H * 320;          // 384,000 shorts (transposed, K padded)

typedef __attribute__((ext_vector_type(8))) short bf16x8;
typedef __attribute__((ext_vector_type(8))) _Float16 f16x8;
typedef __attribute__((ext_vector_type(4))) float f32x4;
typedef unsigned long long ull;

__device__ __forceinline__ short f2bf(float f) {
    unsigned u = __float_as_uint(f);
    u += 0x7fff + ((u >> 16) & 1);   // round-to-nearest-even
    return (short)(u >> 16);
}
__device__ __forceinline__ short f2h(float f) {   // float -> f16 bits (RTNE)
    _Float16 h = (_Float16)f;
    return *(short*)&h;
}
__device__ __forceinline__ float h2f(short s) {
    _Float16 h = *(_Float16*)&s;
    return (float)h;
}
__device__ __forceinline__ float sigm(float x) { return 1.f / (1.f + __expf(-x)); }
__device__ __forceinline__ float tanh_(float x) { return 1.f - 2.f / (__expf(2.f * x) + 1.f); }

// ---------------------------------------------------------------------------
// init: zero exchange tags, c state, out[0]  (ws is poisoned 0xAA every launch)
// ---------------------------------------------------------------------------
__global__ void init_kernel(ull* __restrict__ ex, float* __restrict__ cst,
                            float* __restrict__ out) {
    size_t i = (size_t)blockIdx.x * 256 + threadIdx.x;
    if (i < EX_W) ex[i] = 0ull;
    if (i < CST_F) cst[i] = 0.f;
    if (i == 0) out[0] = 0.f;
}

// ---------------------------------------------------------------------------
// R19 prep: once per launch, hoist all fp32->bf16 conversion + B transpose
// out of zx_gemm's hot loop.
//   emb16[v][k] = f2bf(emb[v][k]) for k<300, 0 for 300<=k<320   (row stride 320)
//   wt[col][k]  = f2bf(Wl[k][col]) for k<300, 0 pad             (transposed)
// SAME f2bf on the same values as R17's in-loop conversion -> MFMA inputs
// bit-identical; absmax must stay 4.8828e-4 exactly.
// ---------------------------------------------------------------------------
__global__ void prep_kernel(const float* __restrict__ emb,
                            const float* __restrict__ Wl,
                            short* __restrict__ emb16, short* __restrict__ wt) {
    const int NE = VV * 40;    // short8 groups in emb16
    const int NW = N4H * 40;   // short8 groups in wt
    for (int j = blockIdx.x * 256 + threadIdx.x; j < NE + NW;
         j += gridDim.x * 256) {
        if (j < NE) {
            int v = j / 40, kb = (j % 40) * 8;
            bf16x8 o;
            if (kb + 8 <= DD) {
                const float* s = emb + (size_t)v * DD + kb;
                float4 a = *(const float4*)s, b = *(const float4*)(s + 4);
                o[0] = f2bf(a.x); o[1] = f2bf(a.y); o[2] = f2bf(a.z); o[3] = f2bf(a.w);
                o[4] = f2bf(b.x); o[5] = f2bf(b.y); o[6] = f2bf(b.z); o[7] = f2bf(b.w);
            } else {
                #pragma unroll
                for (int e = 0; e < 8; ++e) {
                    int k = kb + e;
                    o[e] = (k < DD) ? f2bf(emb[(size_t)v * DD + k]) : (short)0;
                }
            }
            *(bf16x8*)&emb16[(size_t)v * 320 + kb] = o;
        } else {
            int jj = j - NE;
            int col = jj / 40, kb = (jj % 40) * 8;
            bf16x8 o;
            #pragma unroll
            for (int e = 0; e < 8; ++e) {
                int k = kb + e;
                o[e] = (k < DD) ? f2bf(Wl[(size_t)k * N4H + col]) : (short)0;
            }
            *(bf16x8*)&wt[(size_t)col * 320 + kb] = o;
        }
    }
}

// ---------------------------------------------------------------------------
// Phase 1 (R19): zx[b][tc][n] = emb16[ids] @ wt^T + b_lstm   (bf16 MFMA)
// WG tile: M=256 rows, N=80 cols, K=320 (pre-padded). 4 waves, wave = 64x80.
// grid = (32, 15). Changes vs R17:
//   - A-stage: 4x b128 LDS copies per thread (pre-converted bf16, no guards,
//     no f2bf in loop)
//   - B-stage DELETED: fragments load directly from wt (16B/lane, 0.77 MB,
//     L1/L2-resident, shared by all 32 row-WGs of a column tile)
// MFMA + epilogue unchanged.
// ---------------------------------------------------------------------------
__global__ __launch_bounds__(256) void zx_gemm(
    const short* __restrict__ emb16, const int* __restrict__ ids,
    const short* __restrict__ wt, const float* __restrict__ bl,
    float* __restrict__ zx, int t0)
{
    __shared__ short A_l[256 * 40];   // [row][k] pad 32->40 shorts

    const int tid = threadIdx.x;
    const int m0  = blockIdx.x * 256;
    const int n0  = blockIdx.y * 80;
    const int wv  = tid >> 6, ln = tid & 63;

    int myid;
    {   // per-row embedding id (self-use only; register, no LDS)
        int m = m0 + tid;
        int b = m >> 6, tc = m & (CHUNK - 1);
        myid = ids[b * TT + t0 + tc];
    }
    const short* arow = emb16 + (size_t)myid * 320;

    f32x4 acc[4][5];
    for (int i = 0; i < 4; ++i)
        for (int j = 0; j < 5; ++j)
            acc[i][j] = (f32x4){0.f, 0.f, 0.f, 0.f};

    for (int k0 = 0; k0 < 320; k0 += 32) {
        __syncthreads();
        // stage A: 256 rows x 32 k, one row per thread, 4x b128 copies
        {
            #pragma unroll
            for (int q = 0; q < 4; ++q)
                *(bf16x8*)&A_l[tid * 40 + q * 8] =
                    *(const bf16x8*)(arow + k0 + q * 8);
        }
        __syncthreads();
        // fragments + MFMA. A[m=lane&15][k=quad*8+j], B[k=quad*8+j][n=lane&15]
        const int koff = (ln >> 4) * 8;
        bf16x8 afr[4], bfr[5];
        #pragma unroll
        for (int mt = 0; mt < 4; ++mt) {
            int row = wv * 64 + mt * 16 + (ln & 15);
            afr[mt] = *(const bf16x8*)&A_l[row * 40 + koff];
        }
        #pragma unroll
        for (int nt = 0; nt < 5; ++nt) {
            int col = n0 + nt * 16 + (ln & 15);
            bfr[nt] = *(const bf16x8*)&wt[(size_t)col * 320 + k0 + koff];
        }
        #pragma unroll
        for (int mt = 0; mt < 4; ++mt)
            #pragma unroll
            for (int nt = 0; nt < 5; ++nt)
                acc[mt][nt] = __builtin_amdgcn_mfma_f32_16x16x32_bf16(
                    afr[mt], bfr[nt], acc[mt][nt], 0, 0, 0);
    }
    // epilogue: C row=(lane>>4)*4+reg, col=lane&15; add bias
    #pragma unroll
    for (int mt = 0; mt < 4; ++mt) {
        #pragma unroll
        for (int nt = 0; nt < 5; ++nt) {
            #pragma unroll
            for (int rg = 0; rg < 4; ++rg) {
                int row = m0 + wv * 64 + mt * 16 + (ln >> 4) * 4 + rg;
                int col = n0 + nt * 16 + (ln & 15);
                zx[(size_t)row * N4H + col] = acc[mt][nt][rg] + bl[col];
            }
        }
    }
}

// ---------------------------------------------------------------------------
// Phase 2: persistent recurrent kernel. 240 WGs = 16 row-groups x 15 col-groups.
// R17 PROVEN STRUCTURE, byte-identical (R18's sentinel deletion REVERTED:
// sweeps at step start mostly miss -> sentinel wait is real producer-wait;
// ungated speculative retries caused +30us typical and a 30ms outlier).
//
// R12 sentinel-gated polling + per-word tags + parity-2 buffers + single
// barrier per step + R17 payload packing [tag:32 | lo:16 | hi:16].
//
// Recurrent GEMM: F16 MFMA with h-side split (absmax at 4.88e-4 output floor):
//   z = (h_hi + h_lo) @ W_f16,  h_hi = f16(h), h_lo = f16(h - h_hi)
//
// Tag-ABA safety (transitive, per-wave): publish(s+2) > barrier(s+1)
// > all 4 waves detected tags s+1 over window-union = all 15 producers'
// s+1 publishes >= every consumer's step-s reads.
//
// NaN guard (R6): both h planes zeroed IN FULL once per dispatch, so wave 3's
// A reads of cols 300..319 are exact 0 (B=0 there; 0*0=0).
// ---------------------------------------------------------------------------
__global__ __launch_bounds__(256, 1) void lstm_rec(
    const float* __restrict__ zx, const float* __restrict__ Wl,
    const int* __restrict__ lens, ull* __restrict__ ex,
    float* __restrict__ cst, float* __restrict__ hfin, int t0)
{
    const int tid = threadIdx.x;
    const int wv  = tid >> 6, ln = tid & 63;
    const int rg  = blockIdx.x % GR;
    const int cgi = blockIdx.x / GR;
    const int r0  = rg * RPW;
    const int u0  = cgi * UPW;
    const int m   = ln & 15;           // MFMA row / col-in-tile
    const int quad = ln >> 4;

    // producers overlapping wave wv's K-window [96wv, 96wv+96)
    const int pstart_tbl[4] = {0, 4, 9, 14};
    const int np_tbl[4]     = {5, 6, 6, 1};
    const int pstart = pstart_tbl[wv];
    const int np     = np_tbl[wv];

    __shared__ short h_hi[HLB_SIZE];        // f16 hi plane of h_{t-1}
    __shared__ short h_lo[HLB_SIZE];        // f16 lo plane of h_{t-1}
    __shared__ float zp[2][4][RPW][84];     // parity x wave k-partials (pad 80->84)
    __shared__ short w_l[4 * 15 * 64 * 8];  // f16 W_h fragments, frag-ordered

    // ---- one-time: pack W_h f16 B-fragments into LDS ----
    // B[k=quad*8+j][n=lane&15]; frag f = s*5+nt covers kstep s, ntile nt.
    #pragma unroll
    for (int s = 0; s < 3; ++s) {
        #pragma unroll
        for (int nt = 0; nt < 5; ++nt) {
            int c    = nt * 16 + m;            // 0..79 within WG cols
            int gate = c / 20;
            int wcol = 300 * gate + u0 + (c % 20);
            f16x8 b;
            #pragma unroll
            for (int j = 0; j < 8; ++j) {
                int k = KSW * wv + 32 * s + quad * 8 + j;
                float v = (k < HU) ? Wl[(size_t)(DD + k) * N4H + wcol] : 0.f;
                b[j] = (_Float16)v;
            }
            *(f16x8*)&w_l[(((wv * 15) + (s * 5 + nt)) * 64 + ln) * 8] = b;
        }
    }
    const int nks = (wv == 3) ? 1 : 3;   // wave 3: only kstep 0 has real k

    // zero BOTH h planes in full once per dispatch (NaN guard + h0 = 0)
    for (int i = tid; i < HLB_SIZE; i += 256) { h_hi[i] = 0; h_lo[i] = 0; }

    // gate role (tid < 160): u = tid%20, r = tid/20; c/h_old in registers
    const int g_u = tid % UPW, g_r = tid / UPW;
    const bool gl = (tid < RPW * UPW);
    float c_reg = 0.f, ho_reg = 0.f;
    int mylen = 0;
    if (gl) {
        c_reg = cst[(size_t)(r0 + g_r) * HU + u0 + g_u];
        mylen = lens[r0 + g_r];
        if (t0 > 0) {   // reload own h_{t0-1} (tag t0, parity t0&1) from last dispatch
            ull v = __hip_atomic_load(
                ex + (((size_t)(t0 & 1) * GR + rg) * RPW + g_r) * HU + u0 + g_u,
                __ATOMIC_RELAXED, __HIP_MEMORY_SCOPE_AGENT);
            unsigned d = (unsigned)v;
            ho_reg = h2f((short)(d & 0xFFFFu)) + h2f((short)(d >> 16));
        }
    }
    __syncthreads();   // h-plane zero + w_l pack visible before first step

    for (int tc = 0; tc < CHUNK; ++tc) {
        const int t = t0 + tc;
        const int par = t & 1;

        // prefetch zx for this step (independent of h)
        float z_pre[4];
        if (gl) {
            const float* zrow = zx + ((size_t)(r0 + g_r) * CHUNK + tc) * N4H;
            #pragma unroll
            for (int gg = 0; gg < 4; ++gg)
                z_pre[gg] = zrow[300 * gg + u0 + g_u];
        }

        // ---- per-wave stage of OWN K-window stripe (no barrier after) ----
        if (t > 0) {
            const ull* exb = ex + ((size_t)par * GR + rg) * (RPW * HU);

            // phase 1: sentinel spin — lane l polls producer pstart+l (word
            // r=0, u=20p). Cheap (<=6 lines/wave/sweep vs 96 for a full pass).
            if (ln < np) {
                const ull* sp = exb + (pstart + ln) * UPW;
                while ((int)(__hip_atomic_load(sp, __ATOMIC_RELAXED,
                             __HIP_MEMORY_SCOPE_AGENT) >> 32) < t)
                    __builtin_amdgcn_s_sleep(1);
            }

            // phase 2+3: full stripe pass (typically 1 sweep) + straggler poll
            if (wv < 3) {
                // 768 words: i = ln + 64k, r = i/96, u = 96*wv + i%96
                unsigned pend = 0xFFFu;
                do {
                    ull v[12];
                    #pragma unroll
                    for (int k = 0; k < 12; ++k)
                        if ((pend >> k) & 1) {
                            int i = ln + (k << 6);
                            int r = i / 96, u = KSW * wv + (i % 96);
                            v[k] = __hip_atomic_load(exb + r * HU + u,
                                                     __ATOMIC_RELAXED,
                                                     __HIP_MEMORY_SCOPE_AGENT);
                        }
                    unsigned got = 0;
                    #pragma unroll
                    for (int k = 0; k < 12; ++k) {
                        if (((pend >> k) & 1) && (int)(v[k] >> 32) >= t) {
                            int i = ln + (k << 6);
                            int r = i / 96, u = KSW * wv + (i % 96);
                            int idx = r * HLB_STRIDE + u;
                            unsigned d = (unsigned)v[k];
                            h_hi[idx] = (short)(d & 0xFFFFu);
                            h_lo[idx] = (short)(d >> 16);
                            got |= 1u << k;
                        }
                    }
                    pend &= ~got;
                    if (pend) __builtin_amdgcn_s_sleep(1);
                } while (pend);
            } else {
                // 96 words: i = ln + 64k (i<96), r = i/12, u = 288 + i%12
                unsigned pend = (ln < 32) ? 0x3u : 0x1u;
                do {
                    ull v[2];
                    #pragma unroll
                    for (int k = 0; k < 2; ++k)
                        if ((pend >> k) & 1) {
                            int i = ln + (k << 6);
                            int r = i / 12, u = 288 + (i % 12);
                            v[k] = __hip_atomic_load(exb + r * HU + u,
                                                     __ATOMIC_RELAXED,
                                                     __HIP_MEMORY_SCOPE_AGENT);
                        }
                    unsigned got = 0;
                    #pragma unroll
                    for (int k = 0; k < 2; ++k) {
                        if (((pend >> k) & 1) && (int)(v[k] >> 32) >= t) {
                            int i = ln + (k << 6);
                            int r = i / 12, u = 288 + (i % 12);
                            int idx = r * HLB_STRIDE + u;
                            unsigned d = (unsigned)v[k];
                            h_hi[idx] = (short)(d & 0xFFFFu);
                            h_lo[idx] = (short)(d >> 16);
                            got |= 1u << k;
                        }
                    }
                    pend &= ~got;
                    if (pend) __builtin_amdgcn_s_sleep(1);
                } while (pend);
            }
        }

        // ---- MFMA on own stripe: A hi/lo from LDS, B f16 from LDS ----
        f32x4 acc[5];
        #pragma unroll
        for (int nt = 0; nt < 5; ++nt) acc[nt] = (f32x4){0.f, 0.f, 0.f, 0.f};
        for (int s = 0; s < nks; ++s) {
            const int aoff = m * HLB_STRIDE + KSW * wv + 32 * s + quad * 8;
            f16x8 ah = *(const f16x8*)&h_hi[aoff];
            f16x8 al = *(const f16x8*)&h_lo[aoff];
            f16x8 bfr[5];
            #pragma unroll
            for (int nt = 0; nt < 5; ++nt)
                bfr[nt] = *(const f16x8*)&w_l[(((wv * 15) + (s * 5 + nt)) * 64 + ln) * 8];
            #pragma unroll
            for (int nt = 0; nt < 5; ++nt)
                acc[nt] = __builtin_amdgcn_mfma_f32_16x16x32_f16(
                    ah, bfr[nt], acc[nt], 0, 0, 0);
            #pragma unroll
            for (int nt = 0; nt < 5; ++nt)
                acc[nt] = __builtin_amdgcn_mfma_f32_16x16x32_f16(
                    al, bfr[nt], acc[nt], 0, 0, 0);
        }
        // C: row=quad*4+reg (lanes 0-31 -> rows 0-7), col=nt*16+m
        if (ln < 32) {
            #pragma unroll
            for (int nt = 0; nt < 5; ++nt)
                #pragma unroll
                for (int r4 = 0; r4 < 4; ++r4)
                    zp[par][wv][quad * 4 + r4][nt * 16 + m] = acc[nt][r4];
        }
        __syncthreads();   // the ONE barrier: zp(t) visible to gate lanes

        // ---- reduce 4 partials + gates + tagged publish (160 threads) ----
        if (gl) {
            const int b = r0 + g_r;
            float z4[4];
            #pragma unroll
            for (int gg = 0; gg < 4; ++gg) {
                int cidx = gg * UPW + g_u;
                z4[gg] = z_pre[gg] + zp[par][0][g_r][cidx] + zp[par][1][g_r][cidx]
                                   + zp[par][2][g_r][cidx] + zp[par][3][g_r][cidx];
            }
            float ig = sigm(z4[0]);
            float jg = tanh_(z4[1]);
            float fg = sigm(z4[2] + 1.0f);   // FORGET_BIAS
            float og = sigm(z4[3]);
            float c_new = c_reg * fg + ig * jg;
            float h_new = tanh_(c_new) * og;
            bool upd = (t < mylen);
            ho_reg = upd ? h_new : ho_reg;
            c_reg  = upd ? c_new : c_reg;
            // publish h_t (tag t+1, parity (t+1)&1), producer-side hi/lo split:
            // [tag:32 | lo:16 | hi:16] — fire & forget (R17; proven R13/R14)
            short hhi = f2h(ho_reg);
            short hlo = f2h(ho_reg - h2f(hhi));
            ull pk = ((ull)(unsigned)(t + 1) << 32)
                   | ((ull)(unsigned short)hlo << 16) | (ull)(unsigned short)hhi;
            __hip_atomic_store(
                ex + (((size_t)((t + 1) & 1) * GR + rg) * RPW + g_r) * HU + u0 + g_u,
                pk, __ATOMIC_RELAXED, __HIP_MEMORY_SCOPE_AGENT);
            if (tc == CHUNK - 1) hfin[(size_t)b * HU + u0 + g_u] = ho_reg;
        }
        // no trailing barrier: per-wave detect + the single barrier order all
        // h-stripe and zp reuse (see header proof).
    }
    if (gl) cst[(size_t)(r0 + g_r) * HU + u0 + g_u] = c_reg;
}

// ---------------------------------------------------------------------------
// Phase 3: logits = h_final @ W_dense + b_dense; log-softmax NLL; mean loss.
// One wave per batch row.
// ---------------------------------------------------------------------------
__global__ __launch_bounds__(64) void cls_kernel(
    const float* __restrict__ hfin, const float* __restrict__ Wd,
    const float* __restrict__ bd, const int* __restrict__ labels,
    float* __restrict__ out)
{
    const int b = blockIdx.x;
    const int ln = threadIdx.x;
    const float* h = hfin + (size_t)b * HU;
    float p0 = 0.f, p1 = 0.f, p2 = 0.f;
    for (int k = ln; k < HU; k += 64) {
        float hv = h[k];
        p0 += hv * Wd[k * 3 + 0];
        p1 += hv * Wd[k * 3 + 1];
        p2 += hv * Wd[k * 3 + 2];
    }
    #pragma unroll
    for (int off = 32; off > 0; off >>= 1) {
        p0 += __shfl_down(p0, off);
        p1 += __shfl_down(p1, off);
        p2 += __shfl_down(p2, off);
    }
    if (ln == 0) {
        float l0 = p0 + bd[0], l1 = p1 + bd[1], l2 = p2 + bd[2];
        float m = fmaxf(l0, fmaxf(l1, l2));
        float lse = m + logf(__expf(l0 - m) + __expf(l1 - m) + __expf(l2 - m));
        int lab = labels[b];
        float sel = (lab == 0) ? l0 : ((lab == 1) ? l1 : l2);
        float nll = lse - sel;
        out[1 + b * 3 + 0] = l0;
        out[1 + b * 3 + 1] = l1;
        out[1 + b * 3 + 2] = l2;
        atomicAdd(out, nll * (1.0f / BB));
    }
}

// ---------------------------------------------------------------------------
extern "C" void kernel_launch(void* const* d_in, const int* in_sizes, int n_in,
                              void* d_out, int out_size, void* d_ws, size_t ws_size,
                              hipStream_t stream) {
    const int*   ids  = (const int*)d_in[0];
    const int*   lens = (const int*)d_in[1];
    const int*   labs = (const int*)d_in[2];
    const float* emb  = (const float*)d_in[3];
    const float* Wl   = (const float*)d_in[4];
    const float* bl   = (const float*)d_in[5];
    const float* Wd   = (const float*)d_in[6];
    const float* bd   = (const float*)d_in[7];
    float* out = (float*)d_out;

    float* zx    = (float*)d_ws;
    ull*   ex    = (ull*)(zx + ZX_F);
    float* cst   = (float*)(ex + EX_W);
    float* hfin  = cst + CST_F;
    short* emb16 = (short*)(hfin + HFIN_F);
    short* wt    = emb16 + EMB16_W;

    {   // zero exchange tags / c state / out[0]
        int n = (int)((EX_W + 255) / 256);
        init_kernel<<<n, 256, 0, stream>>>(ex, cst, out);
    }
    // R19: one-time bf16 conversion + transpose (emb16, wt)
    prep_kernel<<<2048, 256, 0, stream>>>(emb, Wl, emb16, wt);

    for (int c = 0; c < NCHUNK; ++c) {
        int t0 = c * CHUNK;
        zx_gemm<<<dim3(32, 15), 256, 0, stream>>>(emb16, ids, wt, bl, zx, t0);
        lstm_rec<<<GR * GC, 256, 0, stream>>>(zx, Wl, lens, ex, cst, hfin, t0);
    }
    cls_kernel<<<BB, 64, 0, stream>>>(hfin, Wd, bd, labs, out);
}

// Round 10
// 2210.619 us; speedup vs baseline: 1.1607x; 1.0070x over previous
//
#include <hip/hip_runtime.h>
#include <hip/hip_bf16.h>
#include <math.h>

// Problem constants
#define VV   32000
#define DD   300
#define HU   300
#define NC   3
#define BB   128
#define TT   512
#define N4H  1200
#define CHUNK 64
#define NCHUNK (TT / CHUNK)

// Recurrent kernel partition (round-0 proven structure)
#define GC   15   // col groups (units)
#define GR   16   // row groups
#define RPW  8    // rows per WG (BB/GR)
#define UPW  20   // units per WG (HU/GC)
#define KSW  96   // k-window per wave (4 waves x 96 covers 300 w/ zero pad)
#define HLB_STRIDE 312            // h plane row stride in shorts (624B: 16B-aligned, 2-way bank alias = free)
#define HLB_SIZE   (16 * HLB_STRIDE + 32)

// Workspace layout: [zx f32][ex ull][cst f32][hfin f32][emb16 bf16][wt bf16]
// R21: zx sized for ALL 512 steps when ws_size permits (full mode, one rec
// dispatch); otherwise per-chunk (64 steps, exact R19 behavior).
static constexpr size_t ZX_CHUNK_F = (size_t)BB * CHUNK * N4H;  //  9,830,400 floats
static constexpr size_t ZX_FULL_F  = (size_t)BB * TT * N4H;     // 78,643,200 floats
static constexpr size_t EX_W    = (size_t)2 * GR * RPW * HU;    // 76,800 ulongs (R17 8B/unit)
static constexpr size_t CST_F   = (size_t)BB * HU;              // 38,400 floats
static constexpr size_t HFIN_F  = (size_t)BB * HU;              // 38,400 floats
static constexpr size_t EMB16_W = (size_t)VV * 320;             // 10,240,000 shorts (K padded)
static constexpr size_t WT_W    = (size_t)N4H * 320;            // 384,000 shorts (transposed, K padded)

typedef __attribute__((ext_vector_type(8))) short bf16x8;
typedef __attribute__((ext_vector_type(8))) _Float16 f16x8;
typedef __attribute__((ext_vector_type(4))) float f32x4;
typedef unsigned long long ull;

__device__ __forceinline__ short f2bf(float f) {
    unsigned u = __float_as_uint(f);
    u += 0x7fff + ((u >> 16) & 1);   // round-to-nearest-even
    return (short)(u >> 16);
}
__device__ __forceinline__ short f2h(float f) {   // float -> f16 bits (RTNE)
    _Float16 h = (_Float16)f;
    return *(short*)&h;
}
__device__ __forceinline__ float h2f(short s) {
    _Float16 h = *(_Float16*)&s;
    return (float)h;
}
__device__ __forceinline__ float sigm(float x) { return 1.f / (1.f + __expf(-x)); }
__device__ __forceinline__ float tanh_(float x) { return 1.f - 2.f / (__expf(2.f * x) + 1.f); }

// ---------------------------------------------------------------------------
// init: zero exchange tags, c state, out[0]  (ws is poisoned 0xAA every launch)
// ---------------------------------------------------------------------------
__global__ void init_kernel(ull* __restrict__ ex, float* __restrict__ cst,
                            float* __restrict__ out) {
    size_t i = (size_t)blockIdx.x * 256 + threadIdx.x;
    if (i < EX_W) ex[i] = 0ull;
    if (i < CST_F) cst[i] = 0.f;
    if (i == 0) out[0] = 0.f;
}

// ---------------------------------------------------------------------------
// R19 prep: once per launch, hoist all fp32->bf16 conversion + B transpose
// out of zx_gemm's hot loop. (verified R19: bit-identical MFMA inputs)
// ---------------------------------------------------------------------------
__global__ void prep_kernel(const float* __restrict__ emb,
                            const float* __restrict__ Wl,
                            short* __restrict__ emb16, short* __restrict__ wt) {
    const int NE = VV * 40;    // short8 groups in emb16
    const int NW = N4H * 40;   // short8 groups in wt
    for (int j = blockIdx.x * 256 + threadIdx.x; j < NE + NW;
         j += gridDim.x * 256) {
        if (j < NE) {
            int v = j / 40, kb = (j % 40) * 8;
            bf16x8 o;
            if (kb + 8 <= DD) {
                const float* s = emb + (size_t)v * DD + kb;
                float4 a = *(const float4*)s, b = *(const float4*)(s + 4);
                o[0] = f2bf(a.x); o[1] = f2bf(a.y); o[2] = f2bf(a.z); o[3] = f2bf(a.w);
                o[4] = f2bf(b.x); o[5] = f2bf(b.y); o[6] = f2bf(b.z); o[7] = f2bf(b.w);
            } else {
                #pragma unroll
                for (int e = 0; e < 8; ++e) {
                    int k = kb + e;
                    o[e] = (k < DD) ? f2bf(emb[(size_t)v * DD + k]) : (short)0;
                }
            }
            *(bf16x8*)&emb16[(size_t)v * 320 + kb] = o;
        } else {
            int jj = j - NE;
            int col = jj / 40, kb = (jj % 40) * 8;
            bf16x8 o;
            #pragma unroll
            for (int e = 0; e < 8; ++e) {
                int k = kb + e;
                o[e] = (k < DD) ? f2bf(Wl[(size_t)k * N4H + col]) : (short)0;
            }
            *(bf16x8*)&wt[(size_t)col * 320 + kb] = o;
        }
    }
}

// ---------------------------------------------------------------------------
// Phase 1 (R19 verified; R21 parameterized): zx = emb16[ids] @ wt^T + b_lstm
// Row m encodes (b, tc): b = m >> sdbits, tc = m & (SD-1); zx row = b*SD+tc.
// grid = (BB*SD/256, 15). Chunked mode: sdbits=6 (R19-identical); full: 9.
// ---------------------------------------------------------------------------
__global__ __launch_bounds__(256) void zx_gemm(
    const short* __restrict__ emb16, const int* __restrict__ ids,
    const short* __restrict__ wt, const float* __restrict__ bl,
    float* __restrict__ zx, int t0, int sdbits)
{
    __shared__ short A_l[256 * 40];   // [row][k] pad 32->40 shorts

    const int tid = threadIdx.x;
    const int m0  = blockIdx.x * 256;
    const int n0  = blockIdx.y * 80;
    const int wv  = tid >> 6, ln = tid & 63;

    int myid;
    {   // per-row embedding id (self-use only; register, no LDS)
        int m = m0 + tid;
        int b = m >> sdbits, tc = m & ((1 << sdbits) - 1);
        myid = ids[b * TT + t0 + tc];
    }
    const short* arow = emb16 + (size_t)myid * 320;

    f32x4 acc[4][5];
    for (int i = 0; i < 4; ++i)
        for (int j = 0; j < 5; ++j)
            acc[i][j] = (f32x4){0.f, 0.f, 0.f, 0.f};

    for (int k0 = 0; k0 < 320; k0 += 32) {
        __syncthreads();
        // stage A: 256 rows x 32 k, one row per thread, 4x b128 copies
        {
            #pragma unroll
            for (int q = 0; q < 4; ++q)
                *(bf16x8*)&A_l[tid * 40 + q * 8] =
                    *(const bf16x8*)(arow + k0 + q * 8);
        }
        __syncthreads();
        // fragments + MFMA. A[m=lane&15][k=quad*8+j], B[k=quad*8+j][n=lane&15]
        const int koff = (ln >> 4) * 8;
        bf16x8 afr[4], bfr[5];
        #pragma unroll
        for (int mt = 0; mt < 4; ++mt) {
            int row = wv * 64 + mt * 16 + (ln & 15);
            afr[mt] = *(const bf16x8*)&A_l[row * 40 + koff];
        }
        #pragma unroll
        for (int nt = 0; nt < 5; ++nt) {
            int col = n0 + nt * 16 + (ln & 15);
            bfr[nt] = *(const bf16x8*)&wt[(size_t)col * 320 + k0 + koff];
        }
        #pragma unroll
        for (int mt = 0; mt < 4; ++mt)
            #pragma unroll
            for (int nt = 0; nt < 5; ++nt)
                acc[mt][nt] = __builtin_amdgcn_mfma_f32_16x16x32_bf16(
                    afr[mt], bfr[nt], acc[mt][nt], 0, 0, 0);
    }
    // epilogue: C row=(lane>>4)*4+reg, col=lane&15; add bias
    #pragma unroll
    for (int mt = 0; mt < 4; ++mt) {
        #pragma unroll
        for (int nt = 0; nt < 5; ++nt) {
            #pragma unroll
            for (int rg = 0; rg < 4; ++rg) {
                int row = m0 + wv * 64 + mt * 16 + (ln >> 4) * 4 + rg;
                int col = n0 + nt * 16 + (ln & 15);
                zx[(size_t)row * N4H + col] = acc[mt][nt][rg] + bl[col];
            }
        }
    }
}

// ---------------------------------------------------------------------------
// Phase 2: persistent recurrent kernel. 240 WGs = 16 row-groups x 15 col-groups.
// R17 PROVEN PROTOCOL, byte-identical logic: R12 sentinel-gated polling,
// per-word tags, parity-2 buffers, single barrier per step, hi/lo f16 h split
// (R20 POST-MORTEM: single-f16 h FAILED 1.11e-1 — h quantization noise is
// recurrently amplified over 512 steps; >=22 significand bits are load-
// bearing; exchange stays 8B/unit [tag:32 | lo:16 | hi:16]).
//
// R21: parameterized (t0, nsteps, sdbits) so one dispatch can run ALL 512
// steps when zx is precomputed in full (tags 1..512 monotone within the
// launch; parity-2 + transitive ABA proof unchanged; the cross-dispatch
// reload path simply never triggers at t0=0).
//
// Recurrent GEMM: F16 MFMA with h-side split (absmax at 4.88e-4 output floor):
//   z = (h_hi + h_lo) @ W_f16,  h_hi = f16(h), h_lo = f16(h - h_hi)
//
// Tag-ABA safety (transitive, per-wave): publish(s+2) > barrier(s+1)
// > all 4 waves detected tags s+1 over window-union = all 15 producers'
// s+1 publishes >= every consumer's step-s reads.
//
// NaN guard (R6): both h planes zeroed IN FULL once per dispatch, so wave 3's
// A reads of cols 300..319 are exact 0 (B=0 there; 0*0=0). Sweeps only write
// u<300, so pad columns stay zero for all nsteps.
// ---------------------------------------------------------------------------
__global__ __launch_bounds__(256, 1) void lstm_rec(
    const float* __restrict__ zx, const float* __restrict__ Wl,
    const int* __restrict__ lens, ull* __restrict__ ex,
    float* __restrict__ cst, float* __restrict__ hfin,
    int t0, int nsteps, int sdbits)
{
    const int tid = threadIdx.x;
    const int wv  = tid >> 6, ln = tid & 63;
    const int rg  = blockIdx.x % GR;
    const int cgi = blockIdx.x / GR;
    const int r0  = rg * RPW;
    const int u0  = cgi * UPW;
    const int m   = ln & 15;           // MFMA row / col-in-tile
    const int quad = ln >> 4;

    // producers overlapping wave wv's K-window [96wv, 96wv+96)
    const int pstart_tbl[4] = {0, 4, 9, 14};
    const int np_tbl[4]     = {5, 6, 6, 1};
    const int pstart = pstart_tbl[wv];
    const int np     = np_tbl[wv];

    __shared__ short h_hi[HLB_SIZE];        // f16 hi plane of h_{t-1}
    __shared__ short h_lo[HLB_SIZE];        // f16 lo plane of h_{t-1}
    __shared__ float zp[2][4][RPW][84];     // parity x wave k-partials (pad 80->84)
    __shared__ short w_l[4 * 15 * 64 * 8];  // f16 W_h fragments, frag-ordered

    // ---- one-time: pack W_h f16 B-fragments into LDS ----
    // B[k=quad*8+j][n=lane&15]; frag f = s*5+nt covers kstep s, ntile nt.
    #pragma unroll
    for (int s = 0; s < 3; ++s) {
        #pragma unroll
        for (int nt = 0; nt < 5; ++nt) {
            int c    = nt * 16 + m;            // 0..79 within WG cols
            int gate = c / 20;
            int wcol = 300 * gate + u0 + (c % 20);
            f16x8 b;
            #pragma unroll
            for (int j = 0; j < 8; ++j) {
                int k = KSW * wv + 32 * s + quad * 8 + j;
                float v = (k < HU) ? Wl[(size_t)(DD + k) * N4H + wcol] : 0.f;
                b[j] = (_Float16)v;
            }
            *(f16x8*)&w_l[(((wv * 15) + (s * 5 + nt)) * 64 + ln) * 8] = b;
        }
    }
    const int nks = (wv == 3) ? 1 : 3;   // wave 3: only kstep 0 has real k

    // zero BOTH h planes in full once per dispatch (NaN guard + h0 = 0)
    for (int i = tid; i < HLB_SIZE; i += 256) { h_hi[i] = 0; h_lo[i] = 0; }

    // gate role (tid < 160): u = tid%20, r = tid/20; c/h_old in registers
    const int g_u = tid % UPW, g_r = tid / UPW;
    const bool gl = (tid < RPW * UPW);
    float c_reg = 0.f, ho_reg = 0.f;
    int mylen = 0;
    if (gl) {
        c_reg = cst[(size_t)(r0 + g_r) * HU + u0 + g_u];
        mylen = lens[r0 + g_r];
        if (t0 > 0) {   // reload own h_{t0-1} (tag t0, parity t0&1) from last dispatch
            ull v = __hip_atomic_load(
                ex + (((size_t)(t0 & 1) * GR + rg) * RPW + g_r) * HU + u0 + g_u,
                __ATOMIC_RELAXED, __HIP_MEMORY_SCOPE_AGENT);
            unsigned d = (unsigned)v;
            ho_reg = h2f((short)(d & 0xFFFFu)) + h2f((short)(d >> 16));
        }
    }
    __syncthreads();   // h-plane zero + w_l pack visible before first step

    for (int tc = 0; tc < nsteps; ++tc) {
        const int t = t0 + tc;
        const int par = t & 1;

        // prefetch zx for this step (independent of h)
        float z_pre[4];
        if (gl) {
            const float* zrow = zx
                + (((size_t)(r0 + g_r) << sdbits) + tc) * N4H;
            #pragma unroll
            for (int gg = 0; gg < 4; ++gg)
                z_pre[gg] = zrow[300 * gg + u0 + g_u];
        }

        // ---- per-wave stage of OWN K-window stripe (no barrier after) ----
        if (t > 0) {
            const ull* exb = ex + ((size_t)par * GR + rg) * (RPW * HU);

            // phase 1: sentinel spin — lane l polls producer pstart+l (word
            // r=0, u=20p). Cheap (<=6 lines/wave/sweep vs 96 for a full pass).
            if (ln < np) {
                const ull* sp = exb + (pstart + ln) * UPW;
                while ((int)(__hip_atomic_load(sp, __ATOMIC_RELAXED,
                             __HIP_MEMORY_SCOPE_AGENT) >> 32) < t)
                    __builtin_amdgcn_s_sleep(1);
            }

            // phase 2+3: full stripe pass (typically 1 sweep) + straggler poll
            if (wv < 3) {
                // 768 words: i = ln + 64k, r = i/96, u = 96*wv + i%96
                unsigned pend = 0xFFFu;
                do {
                    ull v[12];
                    #pragma unroll
                    for (int k = 0; k < 12; ++k)
                        if ((pend >> k) & 1) {
                            int i = ln + (k << 6);
                            int r = i / 96, u = KSW * wv + (i % 96);
                            v[k] = __hip_atomic_load(exb + r * HU + u,
                                                     __ATOMIC_RELAXED,
                                                     __HIP_MEMORY_SCOPE_AGENT);
                        }
                    unsigned got = 0;
                    #pragma unroll
                    for (int k = 0; k < 12; ++k) {
                        if (((pend >> k) & 1) && (int)(v[k] >> 32) >= t) {
                            int i = ln + (k << 6);
                            int r = i / 96, u = KSW * wv + (i % 96);
                            int idx = r * HLB_STRIDE + u;
                            unsigned d = (unsigned)v[k];
                            h_hi[idx] = (short)(d & 0xFFFFu);
                            h_lo[idx] = (short)(d >> 16);
                            got |= 1u << k;
                        }
                    }
                    pend &= ~got;
                    if (pend) __builtin_amdgcn_s_sleep(1);
                } while (pend);
            } else {
                // 96 words: i = ln + 64k (i<96), r = i/12, u = 288 + i%12
                unsigned pend = (ln < 32) ? 0x3u : 0x1u;
                do {
                    ull v[2];
                    #pragma unroll
                    for (int k = 0; k < 2; ++k)
                        if ((pend >> k) & 1) {
                            int i = ln + (k << 6);
                            int r = i / 12, u = 288 + (i % 12);
                            v[k] = __hip_atomic_load(exb + r * HU + u,
                                                     __ATOMIC_RELAXED,
                                                     __HIP_MEMORY_SCOPE_AGENT);
                        }
                    unsigned got = 0;
                    #pragma unroll
                    for (int k = 0; k < 2; ++k) {
                        if (((pend >> k) & 1) && (int)(v[k] >> 32) >= t) {
                            int i = ln + (k << 6);
                            int r = i / 12, u = 288 + (i % 12);
                            int idx = r * HLB_STRIDE + u;
                            unsigned d = (unsigned)v[k];
                            h_hi[idx] = (short)(d & 0xFFFFu);
                            h_lo[idx] = (short)(d >> 16);
                            got |= 1u << k;
                        }
                    }
                    pend &= ~got;
                    if (pend) __builtin_amdgcn_s_sleep(1);
                } while (pend);
            }
        }

        // ---- MFMA on own stripe: A hi/lo from LDS, B f16 from LDS ----
        f32x4 acc[5];
        #pragma unroll
        for (int nt = 0; nt < 5; ++nt) acc[nt] = (f32x4){0.f, 0.f, 0.f, 0.f};
        for (int s = 0; s < nks; ++s) {
            const int aoff = m * HLB_STRIDE + KSW * wv + 32 * s + quad * 8;
            f16x8 ah = *(const f16x8*)&h_hi[aoff];
            f16x8 al = *(const f16x8*)&h_lo[aoff];
            f16x8 bfr[5];
            #pragma unroll
            for (int nt = 0; nt < 5; ++nt)
                bfr[nt] = *(const f16x8*)&w_l[(((wv * 15) + (s * 5 + nt)) * 64 + ln) * 8];
            #pragma unroll
            for (int nt = 0; nt < 5; ++nt)
                acc[nt] = __builtin_amdgcn_mfma_f32_16x16x32_f16(
                    ah, bfr[nt], acc[nt], 0, 0, 0);
            #pragma unroll
            for (int nt = 0; nt < 5; ++nt)
                acc[nt] = __builtin_amdgcn_mfma_f32_16x16x32_f16(
                    al, bfr[nt], acc[nt], 0, 0, 0);
        }
        // C: row=quad*4+reg (lanes 0-31 -> rows 0-7), col=nt*16+m
        if (ln < 32) {
            #pragma unroll
            for (int nt = 0; nt < 5; ++nt)
                #pragma unroll
                for (int r4 = 0; r4 < 4; ++r4)
                    zp[par][wv][quad * 4 + r4][nt * 16 + m] = acc[nt][r4];
        }
        __syncthreads();   // the ONE barrier: zp(t) visible to gate lanes

        // ---- reduce 4 partials + gates + tagged publish (160 threads) ----
        if (gl) {
            const int b = r0 + g_r;
            float z4[4];
            #pragma unroll
            for (int gg = 0; gg < 4; ++gg) {
                int cidx = gg * UPW + g_u;
                z4[gg] = z_pre[gg] + zp[par][0][g_r][cidx] + zp[par][1][g_r][cidx]
                                   + zp[par][2][g_r][cidx] + zp[par][3][g_r][cidx];
            }
            float ig = sigm(z4[0]);
            float jg = tanh_(z4[1]);
            float fg = sigm(z4[2] + 1.0f);   // FORGET_BIAS
            float og = sigm(z4[3]);
            float c_new = c_reg * fg + ig * jg;
            float h_new = tanh_(c_new) * og;
            bool upd = (t < mylen);
            ho_reg = upd ? h_new : ho_reg;
            c_reg  = upd ? c_new : c_reg;
            // publish h_t (tag t+1, parity (t+1)&1), producer-side hi/lo split:
            // [tag:32 | lo:16 | hi:16] — fire & forget (R17; proven R13/R14)
            short hhi = f2h(ho_reg);
            short hlo = f2h(ho_reg - h2f(hhi));
            ull pk = ((ull)(unsigned)(t + 1) << 32)
                   | ((ull)(unsigned short)hlo << 16) | (ull)(unsigned short)hhi;
            __hip_atomic_store(
                ex + (((size_t)((t + 1) & 1) * GR + rg) * RPW + g_r) * HU + u0 + g_u,
                pk, __ATOMIC_RELAXED, __HIP_MEMORY_SCOPE_AGENT);
            if (tc == nsteps - 1) hfin[(size_t)b * HU + u0 + g_u] = ho_reg;
        }
        // no trailing barrier: per-wave detect + the single barrier order all
        // h-stripe and zp reuse (see header proof).
    }
    if (gl) cst[(size_t)(r0 + g_r) * HU + u0 + g_u] = c_reg;
}

// ---------------------------------------------------------------------------
// Phase 3: logits = h_final @ W_dense + b_dense; log-softmax NLL; mean loss.
// One wave per batch row.
// ---------------------------------------------------------------------------
__global__ __launch_bounds__(64) void cls_kernel(
    const float* __restrict__ hfin, const float* __restrict__ Wd,
    const float* __restrict__ bd, const int* __restrict__ labels,
    float* __restrict__ out)
{
    const int b = blockIdx.x;
    const int ln = threadIdx.x;
    const float* h = hfin + (size_t)b * HU;
    float p0 = 0.f, p1 = 0.f, p2 = 0.f;
    for (int k = ln; k < HU; k += 64) {
        float hv = h[k];
        p0 += hv * Wd[k * 3 + 0];
        p1 += hv * Wd[k * 3 + 1];
        p2 += hv * Wd[k * 3 + 2];
    }
    #pragma unroll
    for (int off = 32; off > 0; off >>= 1) {
        p0 += __shfl_down(p0, off);
        p1 += __shfl_down(p1, off);
        p2 += __shfl_down(p2, off);
    }
    if (ln == 0) {
        float l0 = p0 + bd[0], l1 = p1 + bd[1], l2 = p2 + bd[2];
        float m = fmaxf(l0, fmaxf(l1, l2));
        float lse = m + logf(__expf(l0 - m) + __expf(l1 - m) + __expf(l2 - m));
        int lab = labels[b];
        float sel = (lab == 0) ? l0 : ((lab == 1) ? l1 : l2);
        float nll = lse - sel;
        out[1 + b * 3 + 0] = l0;
        out[1 + b * 3 + 1] = l1;
        out[1 + b * 3 + 2] = l2;
        atomicAdd(out, nll * (1.0f / BB));
    }
}

// ---------------------------------------------------------------------------
extern "C" void kernel_launch(void* const* d_in, const int* in_sizes, int n_in,
                              void* d_out, int out_size, void* d_ws, size_t ws_size,
                              hipStream_t stream) {
    const int*   ids  = (const int*)d_in[0];
    const int*   lens = (const int*)d_in[1];
    const int*   labs = (const int*)d_in[2];
    const float* emb  = (const float*)d_in[3];
    const float* Wl   = (const float*)d_in[4];
    const float* bl   = (const float*)d_in[5];
    const float* Wd   = (const float*)d_in[6];
    const float* bd   = (const float*)d_in[7];
    float* out = (float*)d_out;

    // R21: full mode (one 512-step rec dispatch) if the workspace fits the
    // full zx; else exact R19 chunked behavior.
    const size_t tail_f = (size_t)(EX_W * 2) + CST_F + HFIN_F   // ex in floats
                        + (EMB16_W + WT_W + 1) / 2;             // shorts->floats
    const bool full = ws_size >= (ZX_FULL_F + tail_f + 1024) * sizeof(float);
    const size_t zxf = full ? ZX_FULL_F : ZX_CHUNK_F;

    float* zx    = (float*)d_ws;
    ull*   ex    = (ull*)(zx + zxf);
    float* cst   = (float*)(ex + EX_W);
    float* hfin  = cst + CST_F;
    short* emb16 = (short*)(hfin + HFIN_F);
    short* wt    = emb16 + EMB16_W;

    {   // zero exchange tags / c state / out[0]
        int n = (int)((EX_W + 255) / 256);
        init_kernel<<<n, 256, 0, stream>>>(ex, cst, out);
    }
    // R19: one-time bf16 conversion + transpose (emb16, wt)
    prep_kernel<<<2048, 256, 0, stream>>>(emb, Wl, emb16, wt);

    if (full) {
        // zx for ALL 512 steps in one launch (3840 WGs), then ONE rec dispatch.
        zx_gemm<<<dim3((BB * TT) / 256, 15), 256, 0, stream>>>(
            emb16, ids, wt, bl, zx, 0, 9);
        lstm_rec<<<GR * GC, 256, 0, stream>>>(zx, Wl, lens, ex, cst, hfin,
                                              0, TT, 9);
    } else {
        for (int c = 0; c < NCHUNK; ++c) {
            int t0 = c * CHUNK;
            zx_gemm<<<dim3((BB * CHUNK) / 256, 15), 256, 0, stream>>>(
                emb16, ids, wt, bl, zx, t0, 6);
            lstm_rec<<<GR * GC, 256, 0, stream>>>(zx, Wl, lens, ex, cst, hfin,
                                                  t0, CHUNK, 6);
        }
    }
    cls_kernel<<<BB, 64, 0, stream>>>(hfin, Wd, bd, labs, out);
}

// Round 11
// 1975.330 us; speedup vs baseline: 1.2990x; 1.1191x over previous
//
#include <hip/hip_runtime.h>
#include <hip/hip_bf16.h>
#include <math.h>

// Problem constants
#define VV   32000
#define DD   300
#define HU   300
#define NC   3
#define BB   128
#define TT   512
#define N4H  1200
#define CHUNK 64
#define NCHUNK (TT / CHUNK)

// Recurrent kernel partition (round-0 proven structure)
#define GC   15   // col groups (units)
#define GR   16   // row groups
#define RPW  8    // rows per WG (BB/GR)
#define UPW  20   // units per WG (HU/GC)
#define KSW  96   // k-window per wave (4 waves x 96 covers 300 w/ zero pad)
#define HLB_STRIDE 312            // h plane row stride in shorts (624B: 16B-aligned, 2-way bank alias = free)
#define HLB_SIZE   (16 * HLB_STRIDE + 32)

// Workspace layout: [zx f32][ex ull][cst f32][hfin f32][emb16 bf16][wt bf16]
// R22: ADAPTIVE chunk size — zx sized for the largest SD in {512,256,128,64}
// that fits ws_size (R21 learned: full 512 needs ~337 MB and did NOT fit;
// fallback ran R19-identical at 2210us). Fewer chunks = fewer dispatch
// boundaries (~15us each: launch + W_l pack + h-zero + state reload + ramp).
static constexpr size_t EX_W    = (size_t)2 * GR * RPW * HU;    // 76,800 ulongs (R17 8B/unit)
static constexpr size_t CST_F   = (size_t)BB * HU;              // 38,400 floats
static constexpr size_t HFIN_F  = (size_t)BB * HU;              // 38,400 floats
static constexpr size_t EMB16_W = (size_t)VV * 320;             // 10,240,000 shorts (K padded)
static constexpr size_t WT_W    = (size_t)N4H * 320;            // 384,000 shorts (transposed, K padded)

typedef __attribute__((ext_vector_type(8))) short bf16x8;
typedef __attribute__((ext_vector_type(8))) _Float16 f16x8;
typedef __attribute__((ext_vector_type(4))) float f32x4;
typedef unsigned long long ull;

__device__ __forceinline__ short f2bf(float f) {
    unsigned u = __float_as_uint(f);
    u += 0x7fff + ((u >> 16) & 1);   // round-to-nearest-even
    return (short)(u >> 16);
}
__device__ __forceinline__ short f2h(float f) {   // float -> f16 bits (RTNE)
    _Float16 h = (_Float16)f;
    return *(short*)&h;
}
__device__ __forceinline__ float h2f(short s) {
    _Float16 h = *(_Float16*)&s;
    return (float)h;
}
__device__ __forceinline__ float sigm(float x) { return 1.f / (1.f + __expf(-x)); }
__device__ __forceinline__ float tanh_(float x) { return 1.f - 2.f / (__expf(2.f * x) + 1.f); }

// ---------------------------------------------------------------------------
// init: zero exchange tags, c state, out[0]  (ws is poisoned 0xAA every launch)
// ---------------------------------------------------------------------------
__global__ void init_kernel(ull* __restrict__ ex, float* __restrict__ cst,
                            float* __restrict__ out) {
    size_t i = (size_t)blockIdx.x * 256 + threadIdx.x;
    if (i < EX_W) ex[i] = 0ull;
    if (i < CST_F) cst[i] = 0.f;
    if (i == 0) out[0] = 0.f;
}

// ---------------------------------------------------------------------------
// R19 prep: once per launch, hoist all fp32->bf16 conversion + B transpose
// out of zx_gemm's hot loop. (verified R19: bit-identical MFMA inputs)
// ---------------------------------------------------------------------------
__global__ void prep_kernel(const float* __restrict__ emb,
                            const float* __restrict__ Wl,
                            short* __restrict__ emb16, short* __restrict__ wt) {
    const int NE = VV * 40;    // short8 groups in emb16
    const int NW = N4H * 40;   // short8 groups in wt
    for (int j = blockIdx.x * 256 + threadIdx.x; j < NE + NW;
         j += gridDim.x * 256) {
        if (j < NE) {
            int v = j / 40, kb = (j % 40) * 8;
            bf16x8 o;
            if (kb + 8 <= DD) {
                const float* s = emb + (size_t)v * DD + kb;
                float4 a = *(const float4*)s, b = *(const float4*)(s + 4);
                o[0] = f2bf(a.x); o[1] = f2bf(a.y); o[2] = f2bf(a.z); o[3] = f2bf(a.w);
                o[4] = f2bf(b.x); o[5] = f2bf(b.y); o[6] = f2bf(b.z); o[7] = f2bf(b.w);
            } else {
                #pragma unroll
                for (int e = 0; e < 8; ++e) {
                    int k = kb + e;
                    o[e] = (k < DD) ? f2bf(emb[(size_t)v * DD + k]) : (short)0;
                }
            }
            *(bf16x8*)&emb16[(size_t)v * 320 + kb] = o;
        } else {
            int jj = j - NE;
            int col = jj / 40, kb = (jj % 40) * 8;
            bf16x8 o;
            #pragma unroll
            for (int e = 0; e < 8; ++e) {
                int k = kb + e;
                o[e] = (k < DD) ? f2bf(Wl[(size_t)k * N4H + col]) : (short)0;
            }
            *(bf16x8*)&wt[(size_t)col * 320 + kb] = o;
        }
    }
}

// ---------------------------------------------------------------------------
// Phase 1 (R19 verified; R21 parameterized): zx = emb16[ids] @ wt^T + b_lstm
// Row m encodes (b, tc): b = m >> sdbits, tc = m & (SD-1); zx row = b*SD+tc.
// grid = (BB*SD/256, 15). sdbits=6 is the R19-identical configuration.
// ---------------------------------------------------------------------------
__global__ __launch_bounds__(256) void zx_gemm(
    const short* __restrict__ emb16, const int* __restrict__ ids,
    const short* __restrict__ wt, const float* __restrict__ bl,
    float* __restrict__ zx, int t0, int sdbits)
{
    __shared__ short A_l[256 * 40];   // [row][k] pad 32->40 shorts

    const int tid = threadIdx.x;
    const int m0  = blockIdx.x * 256;
    const int n0  = blockIdx.y * 80;
    const int wv  = tid >> 6, ln = tid & 63;

    int myid;
    {   // per-row embedding id (self-use only; register, no LDS)
        int m = m0 + tid;
        int b = m >> sdbits, tc = m & ((1 << sdbits) - 1);
        myid = ids[b * TT + t0 + tc];
    }
    const short* arow = emb16 + (size_t)myid * 320;

    f32x4 acc[4][5];
    for (int i = 0; i < 4; ++i)
        for (int j = 0; j < 5; ++j)
            acc[i][j] = (f32x4){0.f, 0.f, 0.f, 0.f};

    for (int k0 = 0; k0 < 320; k0 += 32) {
        __syncthreads();
        // stage A: 256 rows x 32 k, one row per thread, 4x b128 copies
        {
            #pragma unroll
            for (int q = 0; q < 4; ++q)
                *(bf16x8*)&A_l[tid * 40 + q * 8] =
                    *(const bf16x8*)(arow + k0 + q * 8);
        }
        __syncthreads();
        // fragments + MFMA. A[m=lane&15][k=quad*8+j], B[k=quad*8+j][n=lane&15]
        const int koff = (ln >> 4) * 8;
        bf16x8 afr[4], bfr[5];
        #pragma unroll
        for (int mt = 0; mt < 4; ++mt) {
            int row = wv * 64 + mt * 16 + (ln & 15);
            afr[mt] = *(const bf16x8*)&A_l[row * 40 + koff];
        }
        #pragma unroll
        for (int nt = 0; nt < 5; ++nt) {
            int col = n0 + nt * 16 + (ln & 15);
            bfr[nt] = *(const bf16x8*)&wt[(size_t)col * 320 + k0 + koff];
        }
        #pragma unroll
        for (int mt = 0; mt < 4; ++mt)
            #pragma unroll
            for (int nt = 0; nt < 5; ++nt)
                acc[mt][nt] = __builtin_amdgcn_mfma_f32_16x16x32_bf16(
                    afr[mt], bfr[nt], acc[mt][nt], 0, 0, 0);
    }
    // epilogue: C row=(lane>>4)*4+reg, col=lane&15; add bias
    #pragma unroll
    for (int mt = 0; mt < 4; ++mt) {
        #pragma unroll
        for (int nt = 0; nt < 5; ++nt) {
            #pragma unroll
            for (int rg = 0; rg < 4; ++rg) {
                int row = m0 + wv * 64 + mt * 16 + (ln >> 4) * 4 + rg;
                int col = n0 + nt * 16 + (ln & 15);
                zx[(size_t)row * N4H + col] = acc[mt][nt][rg] + bl[col];
            }
        }
    }
}

// ---------------------------------------------------------------------------
// Phase 2: persistent recurrent kernel. 240 WGs = 16 row-groups x 15 col-groups.
// R17 PROVEN PROTOCOL, byte-identical logic: R12 sentinel-gated polling,
// per-word tags, parity-2 buffers, single barrier per step, hi/lo f16 h split
// (R20 POST-MORTEM: single-f16 h FAILED 1.11e-1 — h quantization noise is
// recurrently amplified over 512 steps; >=22 significand bits are load-
// bearing; exchange stays 8B/unit [tag:32 | lo:16 | hi:16]).
//
// R21/R22: parameterized (t0, nsteps, sdbits) so one dispatch runs SD steps,
// SD chosen at launch time by workspace fit. Tags t0+1..t0+SD are monotone
// within a dispatch; the cross-dispatch reload (t0>0: tag t0, parity t0&1 —
// exactly what the previous chunk's last step published, for ANY SD) is the
// same mechanism proven at SD=64 since round 0. Parity-2 + transitive ABA
// proof unchanged.
//
// Recurrent GEMM: F16 MFMA with h-side split (absmax at 4.88e-4 output floor):
//   z = (h_hi + h_lo) @ W_f16,  h_hi = f16(h), h_lo = f16(h - h_hi)
//
// Tag-ABA safety (transitive, per-wave): publish(s+2) > barrier(s+1)
// > all 4 waves detected tags s+1 over window-union = all 15 producers'
// s+1 publishes >= every consumer's step-s reads.
//
// NaN guard (R6): both h planes zeroed IN FULL once per dispatch, so wave 3's
// A reads of cols 300..319 are exact 0 (B=0 there; 0*0=0). Sweeps only write
// u<300, so pad columns stay zero for all nsteps.
// ---------------------------------------------------------------------------
__global__ __launch_bounds__(256, 1) void lstm_rec(
    const float* __restrict__ zx, const float* __restrict__ Wl,
    const int* __restrict__ lens, ull* __restrict__ ex,
    float* __restrict__ cst, float* __restrict__ hfin,
    int t0, int nsteps, int sdbits)
{
    const int tid = threadIdx.x;
    const int wv  = tid >> 6, ln = tid & 63;
    const int rg  = blockIdx.x % GR;
    const int cgi = blockIdx.x / GR;
    const int r0  = rg * RPW;
    const int u0  = cgi * UPW;
    const int m   = ln & 15;           // MFMA row / col-in-tile
    const int quad = ln >> 4;

    // producers overlapping wave wv's K-window [96wv, 96wv+96)
    const int pstart_tbl[4] = {0, 4, 9, 14};
    const int np_tbl[4]     = {5, 6, 6, 1};
    const int pstart = pstart_tbl[wv];
    const int np     = np_tbl[wv];

    __shared__ short h_hi[HLB_SIZE];        // f16 hi plane of h_{t-1}
    __shared__ short h_lo[HLB_SIZE];        // f16 lo plane of h_{t-1}
    __shared__ float zp[2][4][RPW][84];     // parity x wave k-partials (pad 80->84)
    __shared__ short w_l[4 * 15 * 64 * 8];  // f16 W_h fragments, frag-ordered

    // ---- one-time: pack W_h f16 B-fragments into LDS ----
    // B[k=quad*8+j][n=lane&15]; frag f = s*5+nt covers kstep s, ntile nt.
    #pragma unroll
    for (int s = 0; s < 3; ++s) {
        #pragma unroll
        for (int nt = 0; nt < 5; ++nt) {
            int c    = nt * 16 + m;            // 0..79 within WG cols
            int gate = c / 20;
            int wcol = 300 * gate + u0 + (c % 20);
            f16x8 b;
            #pragma unroll
            for (int j = 0; j < 8; ++j) {
                int k = KSW * wv + 32 * s + quad * 8 + j;
                float v = (k < HU) ? Wl[(size_t)(DD + k) * N4H + wcol] : 0.f;
                b[j] = (_Float16)v;
            }
            *(f16x8*)&w_l[(((wv * 15) + (s * 5 + nt)) * 64 + ln) * 8] = b;
        }
    }
    const int nks = (wv == 3) ? 1 : 3;   // wave 3: only kstep 0 has real k

    // zero BOTH h planes in full once per dispatch (NaN guard + h0 = 0)
    for (int i = tid; i < HLB_SIZE; i += 256) { h_hi[i] = 0; h_lo[i] = 0; }

    // gate role (tid < 160): u = tid%20, r = tid/20; c/h_old in registers
    const int g_u = tid % UPW, g_r = tid / UPW;
    const bool gl = (tid < RPW * UPW);
    float c_reg = 0.f, ho_reg = 0.f;
    int mylen = 0;
    if (gl) {
        c_reg = cst[(size_t)(r0 + g_r) * HU + u0 + g_u];
        mylen = lens[r0 + g_r];
        if (t0 > 0) {   // reload own h_{t0-1} (tag t0, parity t0&1) from last dispatch
            ull v = __hip_atomic_load(
                ex + (((size_t)(t0 & 1) * GR + rg) * RPW + g_r) * HU + u0 + g_u,
                __ATOMIC_RELAXED, __HIP_MEMORY_SCOPE_AGENT);
            unsigned d = (unsigned)v;
            ho_reg = h2f((short)(d & 0xFFFFu)) + h2f((short)(d >> 16));
        }
    }
    __syncthreads();   // h-plane zero + w_l pack visible before first step

    for (int tc = 0; tc < nsteps; ++tc) {
        const int t = t0 + tc;
        const int par = t & 1;

        // prefetch zx for this step (independent of h)
        float z_pre[4];
        if (gl) {
            const float* zrow = zx
                + (((size_t)(r0 + g_r) << sdbits) + tc) * N4H;
            #pragma unroll
            for (int gg = 0; gg < 4; ++gg)
                z_pre[gg] = zrow[300 * gg + u0 + g_u];
        }

        // ---- per-wave stage of OWN K-window stripe (no barrier after) ----
        if (t > 0) {
            const ull* exb = ex + ((size_t)par * GR + rg) * (RPW * HU);

            // phase 1: sentinel spin — lane l polls producer pstart+l (word
            // r=0, u=20p). Cheap (<=6 lines/wave/sweep vs 96 for a full pass).
            if (ln < np) {
                const ull* sp = exb + (pstart + ln) * UPW;
                while ((int)(__hip_atomic_load(sp, __ATOMIC_RELAXED,
                             __HIP_MEMORY_SCOPE_AGENT) >> 32) < t)
                    __builtin_amdgcn_s_sleep(1);
            }

            // phase 2+3: full stripe pass (typically 1 sweep) + straggler poll
            if (wv < 3) {
                // 768 words: i = ln + 64k, r = i/96, u = 96*wv + i%96
                unsigned pend = 0xFFFu;
                do {
                    ull v[12];
                    #pragma unroll
                    for (int k = 0; k < 12; ++k)
                        if ((pend >> k) & 1) {
                            int i = ln + (k << 6);
                            int r = i / 96, u = KSW * wv + (i % 96);
                            v[k] = __hip_atomic_load(exb + r * HU + u,
                                                     __ATOMIC_RELAXED,
                                                     __HIP_MEMORY_SCOPE_AGENT);
                        }
                    unsigned got = 0;
                    #pragma unroll
                    for (int k = 0; k < 12; ++k) {
                        if (((pend >> k) & 1) && (int)(v[k] >> 32) >= t) {
                            int i = ln + (k << 6);
                            int r = i / 96, u = KSW * wv + (i % 96);
                            int idx = r * HLB_STRIDE + u;
                            unsigned d = (unsigned)v[k];
                            h_hi[idx] = (short)(d & 0xFFFFu);
                            h_lo[idx] = (short)(d >> 16);
                            got |= 1u << k;
                        }
                    }
                    pend &= ~got;
                    if (pend) __builtin_amdgcn_s_sleep(1);
                } while (pend);
            } else {
                // 96 words: i = ln + 64k (i<96), r = i/12, u = 288 + i%12
                unsigned pend = (ln < 32) ? 0x3u : 0x1u;
                do {
                    ull v[2];
                    #pragma unroll
                    for (int k = 0; k < 2; ++k)
                        if ((pend >> k) & 1) {
                            int i = ln + (k << 6);
                            int r = i / 12, u = 288 + (i % 12);
                            v[k] = __hip_atomic_load(exb + r * HU + u,
                                                     __ATOMIC_RELAXED,
                                                     __HIP_MEMORY_SCOPE_AGENT);
                        }
                    unsigned got = 0;
                    #pragma unroll
                    for (int k = 0; k < 2; ++k) {
                        if (((pend >> k) & 1) && (int)(v[k] >> 32) >= t) {
                            int i = ln + (k << 6);
                            int r = i / 12, u = 288 + (i % 12);
                            int idx = r * HLB_STRIDE + u;
                            unsigned d = (unsigned)v[k];
                            h_hi[idx] = (short)(d & 0xFFFFu);
                            h_lo[idx] = (short)(d >> 16);
                            got |= 1u << k;
                        }
                    }
                    pend &= ~got;
                    if (pend) __builtin_amdgcn_s_sleep(1);
                } while (pend);
            }
        }

        // ---- MFMA on own stripe: A hi/lo from LDS, B f16 from LDS ----
        f32x4 acc[5];
        #pragma unroll
        for (int nt = 0; nt < 5; ++nt) acc[nt] = (f32x4){0.f, 0.f, 0.f, 0.f};
        for (int s = 0; s < nks; ++s) {
            const int aoff = m * HLB_STRIDE + KSW * wv + 32 * s + quad * 8;
            f16x8 ah = *(const f16x8*)&h_hi[aoff];
            f16x8 al = *(const f16x8*)&h_lo[aoff];
            f16x8 bfr[5];
            #pragma unroll
            for (int nt = 0; nt < 5; ++nt)
                bfr[nt] = *(const f16x8*)&w_l[(((wv * 15) + (s * 5 + nt)) * 64 + ln) * 8];
            #pragma unroll
            for (int nt = 0; nt < 5; ++nt)
                acc[nt] = __builtin_amdgcn_mfma_f32_16x16x32_f16(
                    ah, bfr[nt], acc[nt], 0, 0, 0);
            #pragma unroll
            for (int nt = 0; nt < 5; ++nt)
                acc[nt] = __builtin_amdgcn_mfma_f32_16x16x32_f16(
                    al, bfr[nt], acc[nt], 0, 0, 0);
        }
        // C: row=quad*4+reg (lanes 0-31 -> rows 0-7), col=nt*16+m
        if (ln < 32) {
            #pragma unroll
            for (int nt = 0; nt < 5; ++nt)
                #pragma unroll
                for (int r4 = 0; r4 < 4; ++r4)
                    zp[par][wv][quad * 4 + r4][nt * 16 + m] = acc[nt][r4];
        }
        __syncthreads();   // the ONE barrier: zp(t) visible to gate lanes

        // ---- reduce 4 partials + gates + tagged publish (160 threads) ----
        if (gl) {
            const int b = r0 + g_r;
            float z4[4];
            #pragma unroll
            for (int gg = 0; gg < 4; ++gg) {
                int cidx = gg * UPW + g_u;
                z4[gg] = z_pre[gg] + zp[par][0][g_r][cidx] + zp[par][1][g_r][cidx]
                                   + zp[par][2][g_r][cidx] + zp[par][3][g_r][cidx];
            }
            float ig = sigm(z4[0]);
            float jg = tanh_(z4[1]);
            float fg = sigm(z4[2] + 1.0f);   // FORGET_BIAS
            float og = sigm(z4[3]);
            float c_new = c_reg * fg + ig * jg;
            float h_new = tanh_(c_new) * og;
            bool upd = (t < mylen);
            ho_reg = upd ? h_new : ho_reg;
            c_reg  = upd ? c_new : c_reg;
            // publish h_t (tag t+1, parity (t+1)&1), producer-side hi/lo split:
            // [tag:32 | lo:16 | hi:16] — fire & forget (R17; proven R13/R14)
            short hhi = f2h(ho_reg);
            short hlo = f2h(ho_reg - h2f(hhi));
            ull pk = ((ull)(unsigned)(t + 1) << 32)
                   | ((ull)(unsigned short)hlo << 16) | (ull)(unsigned short)hhi;
            __hip_atomic_store(
                ex + (((size_t)((t + 1) & 1) * GR + rg) * RPW + g_r) * HU + u0 + g_u,
                pk, __ATOMIC_RELAXED, __HIP_MEMORY_SCOPE_AGENT);
            if (tc == nsteps - 1) hfin[(size_t)b * HU + u0 + g_u] = ho_reg;
        }
        // no trailing barrier: per-wave detect + the single barrier order all
        // h-stripe and zp reuse (see header proof).
    }
    if (gl) cst[(size_t)(r0 + g_r) * HU + u0 + g_u] = c_reg;
}

// ---------------------------------------------------------------------------
// Phase 3: logits = h_final @ W_dense + b_dense; log-softmax NLL; mean loss.
// One wave per batch row.
// ---------------------------------------------------------------------------
__global__ __launch_bounds__(64) void cls_kernel(
    const float* __restrict__ hfin, const float* __restrict__ Wd,
    const float* __restrict__ bd, const int* __restrict__ labels,
    float* __restrict__ out)
{
    const int b = blockIdx.x;
    const int ln = threadIdx.x;
    const float* h = hfin + (size_t)b * HU;
    float p0 = 0.f, p1 = 0.f, p2 = 0.f;
    for (int k = ln; k < HU; k += 64) {
        float hv = h[k];
        p0 += hv * Wd[k * 3 + 0];
        p1 += hv * Wd[k * 3 + 1];
        p2 += hv * Wd[k * 3 + 2];
    }
    #pragma unroll
    for (int off = 32; off > 0; off >>= 1) {
        p0 += __shfl_down(p0, off);
        p1 += __shfl_down(p1, off);
        p2 += __shfl_down(p2, off);
    }
    if (ln == 0) {
        float l0 = p0 + bd[0], l1 = p1 + bd[1], l2 = p2 + bd[2];
        float m = fmaxf(l0, fmaxf(l1, l2));
        float lse = m + logf(__expf(l0 - m) + __expf(l1 - m) + __expf(l2 - m));
        int lab = labels[b];
        float sel = (lab == 0) ? l0 : ((lab == 1) ? l1 : l2);
        float nll = lse - sel;
        out[1 + b * 3 + 0] = l0;
        out[1 + b * 3 + 1] = l1;
        out[1 + b * 3 + 2] = l2;
        atomicAdd(out, nll * (1.0f / BB));
    }
}

// ---------------------------------------------------------------------------
extern "C" void kernel_launch(void* const* d_in, const int* in_sizes, int n_in,
                              void* d_out, int out_size, void* d_ws, size_t ws_size,
                              hipStream_t stream) {
    const int*   ids  = (const int*)d_in[0];
    const int*   lens = (const int*)d_in[1];
    const int*   labs = (const int*)d_in[2];
    const float* emb  = (const float*)d_in[3];
    const float* Wl   = (const float*)d_in[4];
    const float* bl   = (const float*)d_in[5];
    const float* Wd   = (const float*)d_in[6];
    const float* bd   = (const float*)d_in[7];
    float* out = (float*)d_out;

    // R22: adaptive chunk size — pick the largest SD in {512,256,128,64}
    // whose zx fits ws_size. sdbits=6 (SD=64) is the proven R19 baseline.
    const size_t tail_f = (size_t)(EX_W * 2) + CST_F + HFIN_F   // ex in floats
                        + (EMB16_W + WT_W + 1) / 2;             // shorts->floats
    int sdbits = 6;
    for (int sb = 9; sb > 6; --sb) {
        size_t zxf_c = (size_t)BB * ((size_t)1 << sb) * N4H;
        if (ws_size >= (zxf_c + tail_f + 1024) * sizeof(float)) {
            sdbits = sb;
            break;
        }
    }
    const int SD  = 1 << sdbits;
    const int nch = TT >> sdbits;
    const size_t zxf = (size_t)BB * ((size_t)SD) * N4H;

    float* zx    = (float*)d_ws;
    ull*   ex    = (ull*)(zx + zxf);
    float* cst   = (float*)(ex + EX_W);
    float* hfin  = cst + CST_F;
    short* emb16 = (short*)(hfin + HFIN_F);
    short* wt    = emb16 + EMB16_W;

    {   // zero exchange tags / c state / out[0]
        int n = (int)((EX_W + 255) / 256);
        init_kernel<<<n, 256, 0, stream>>>(ex, cst, out);
    }
    // R19: one-time bf16 conversion + transpose (emb16, wt)
    prep_kernel<<<2048, 256, 0, stream>>>(emb, Wl, emb16, wt);

    for (int c = 0; c < nch; ++c) {
        int t0 = c << sdbits;
        zx_gemm<<<dim3((BB << sdbits) / 256, 15), 256, 0, stream>>>(
            emb16, ids, wt, bl, zx, t0, sdbits);
        lstm_rec<<<GR * GC, 256, 0, stream>>>(zx, Wl, lens, ex, cst, hfin,
                                              t0, SD, sdbits);
    }
    cls_kernel<<<BB, 64, 0, stream>>>(hfin, Wd, bd, labs, out);
}